// Round 4
// baseline (16.407 us; speedup 1.0000x reference)
//
#include <hip/hip_runtime.h>

// dag[i,j] = T[i,j] * (i<j ? 1 : (i>j ? 1-T[j,i] : 0)),  T[i,j] = s[i,j]*nr[j]
// s[i,j]  = (ep[i,j] + ge[i,j,0]) > ((1-ep[i,j]) + ge[i,j,1])
// nr[j]   = 1 - ((rp[j] + gr[j,0]) > ((1-rp[j]) + gr[j,1]))

typedef float f4 __attribute__((ext_vector_type(4)));   // clang vector: OK for nontemporal builtins

constexpr int TS = 32;

__global__ __launch_bounds__(256) void dag_kernel(
    const float* __restrict__ rp,
    const f4*    __restrict__ gr4,   // g_root viewed as f4 (2 nodes/vec)
    const float* __restrict__ ep,
    const f4*    __restrict__ ge4,   // g_edge viewed as f4 (2 pairs/vec)
    float* __restrict__ out, int n)
{
    __shared__ float Ash[TS][TS + 1];   // stride 33 -> transposed read ~2-way (free)

    // triangular pair decode: blocks cover (bi,bj), bi <= bj
    int p = blockIdx.x;
    int a = (int)((sqrtf(8.0f * (float)p + 1.0f) - 1.0f) * 0.5f);
    while ((a + 1) * (a + 2) / 2 <= p) ++a;
    while (a * (a + 1) / 2 > p) --a;
    const int bi = p - a * (a + 1) / 2;
    const int bj = a;
    const int I = bi * TS, J = bj * TS;
    const bool diag = (bi == bj);

    const int t   = threadIdx.x;
    const int row = t >> 3;          // 0..31
    const int c4  = (t & 7) << 2;    // 0,4,...,28

    const size_t idxA = (size_t)(I + row) * n + (size_t)(J + c4);
    const size_t idxB = (size_t)(J + row) * n + (size_t)(I + c4);

    // ---- issue ALL streaming loads up front (max MLP, no barrier above) ----
    const f4 epA = __builtin_nontemporal_load((const f4*)(ep + idxA));
    const f4 qA0 = __builtin_nontemporal_load(ge4 + (idxA >> 1));
    const f4 qA1 = __builtin_nontemporal_load(ge4 + (idxA >> 1) + 1);
    f4 epB, qB0, qB1;
    if (!diag) {
        epB = __builtin_nontemporal_load((const f4*)(ep + idxB));
        qB0 = __builtin_nontemporal_load(ge4 + (idxB >> 1));
        qB1 = __builtin_nontemporal_load(ge4 + (idxB >> 1) + 1);
    }

    // ---- per-thread root indicators (rp/gr are L2-resident; no LDS, no sync) ----
    const f4 rpA = *(const f4*)(rp + J + c4);
    const f4 gA0 = gr4[(J + c4) >> 1];
    const f4 gA1 = gr4[((J + c4) >> 1) + 1];
    float nA[4];
    nA[0] = ((rpA.x + gA0.x) > ((1.0f - rpA.x) + gA0.y)) ? 0.0f : 1.0f;
    nA[1] = ((rpA.y + gA0.z) > ((1.0f - rpA.y) + gA0.w)) ? 0.0f : 1.0f;
    nA[2] = ((rpA.z + gA1.x) > ((1.0f - rpA.z) + gA1.y)) ? 0.0f : 1.0f;
    nA[3] = ((rpA.w + gA1.z) > ((1.0f - rpA.w) + gA1.w)) ? 0.0f : 1.0f;

    // ---- tile A = T[I+row][J+c4 .. +3] ----
    float av[4];
    av[0] = ((epA.x + qA0.x) > ((1.0f - epA.x) + qA0.y)) ? nA[0] : 0.0f;
    av[1] = ((epA.y + qA0.z) > ((1.0f - epA.y) + qA0.w)) ? nA[1] : 0.0f;
    av[2] = ((epA.z + qA1.x) > ((1.0f - epA.z) + qA1.y)) ? nA[2] : 0.0f;
    av[3] = ((epA.w + qA1.z) > ((1.0f - epA.w) + qA1.w)) ? nA[3] : 0.0f;
    Ash[row][c4 + 0] = av[0];
    Ash[row][c4 + 1] = av[1];
    Ash[row][c4 + 2] = av[2];
    Ash[row][c4 + 3] = av[3];

    if (diag) {
        __syncthreads();
        f4 v;
#pragma unroll
        for (int c = 0; c < 4; ++c) {
            int col = c4 + c;
            float x;
            if (row == col)      x = 0.0f;
            else if (row < col)  x = av[c];
            else                 x = av[c] * (1.0f - Ash[col][row]);
            v[c] = x;
        }
        __builtin_nontemporal_store(v, (f4*)(out + idxA));
    } else {
        // upper tile: i = I+row < j = J+col always
        f4 u = {av[0], av[1], av[2], av[3]};
        __builtin_nontemporal_store(u, (f4*)(out + idxA));

        // ---- tile B = T[J+row][I+c4 .. +3] (lower: i' = J+row > j' = I+col) ----
        const f4 rpB = *(const f4*)(rp + I + c4);
        const f4 gB0 = gr4[(I + c4) >> 1];
        const f4 gB1 = gr4[((I + c4) >> 1) + 1];
        float nB[4];
        nB[0] = ((rpB.x + gB0.x) > ((1.0f - rpB.x) + gB0.y)) ? 0.0f : 1.0f;
        nB[1] = ((rpB.y + gB0.z) > ((1.0f - rpB.y) + gB0.w)) ? 0.0f : 1.0f;
        nB[2] = ((rpB.z + gB1.x) > ((1.0f - rpB.z) + gB1.y)) ? 0.0f : 1.0f;
        nB[3] = ((rpB.w + gB1.z) > ((1.0f - rpB.w) + gB1.w)) ? 0.0f : 1.0f;

        float bv[4];
        bv[0] = ((epB.x + qB0.x) > ((1.0f - epB.x) + qB0.y)) ? nB[0] : 0.0f;
        bv[1] = ((epB.y + qB0.z) > ((1.0f - epB.y) + qB0.w)) ? nB[1] : 0.0f;
        bv[2] = ((epB.z + qB1.x) > ((1.0f - epB.z) + qB1.y)) ? nB[2] : 0.0f;
        bv[3] = ((epB.w + qB1.z) > ((1.0f - epB.w) + qB1.w)) ? nB[3] : 0.0f;

        __syncthreads();
        f4 w;
        w.x = bv[0] * (1.0f - Ash[c4 + 0][row]);
        w.y = bv[1] * (1.0f - Ash[c4 + 1][row]);
        w.z = bv[2] * (1.0f - Ash[c4 + 2][row]);
        w.w = bv[3] * (1.0f - Ash[c4 + 3][row]);
        __builtin_nontemporal_store(w, (f4*)(out + idxB));
    }
}

extern "C" void kernel_launch(void* const* d_in, const int* in_sizes, int n_in,
                              void* d_out, int out_size, void* d_ws, size_t ws_size,
                              hipStream_t stream) {
    const float* rp = (const float*)d_in[0];   // root_probs (N)
    const float* ep = (const float*)d_in[1];   // edge_probs (N,N)
    const f4*    gr = (const f4*)d_in[2];      // g_root (N,2) as f4
    const f4*    ge = (const f4*)d_in[3];      // g_edge (N,N,2) as f4
    float* out = (float*)d_out;
    const int n = in_sizes[0];

    const int nb = n / TS;                     // 2048/32 = 64
    const int pairs = nb * (nb + 1) / 2;       // 2080 blocks
    dag_kernel<<<pairs, 256, 0, stream>>>(rp, gr, ep, ge, out, n);
}